// Round 2
// baseline (545.046 us; speedup 1.0000x reference)
//
#include <hip/hip_runtime.h>
#include <math.h>

// Problem constants (B=2, H=W=256, DIM=INNER=64, WS=8, OWS=12, HEADS=4, DH=16)
#define NPIX   65536      // 256*256
#define NPIXT  131072     // B * NPIX
#define NW     1024       // 32*32 windows per batch
#define KEEP   512

// ---------------------------------------------------------------------------
// K1: fused q/k/v 1x1 convs.  Block = 256 px staged in LDS, each thread
// computes all 192 outputs for its pixel in chunks of 16.
// ---------------------------------------------------------------------------
__global__ __launch_bounds__(256) void k_qkv(
    const float* __restrict__ x,
    const float* __restrict__ Wq, const float* __restrict__ bq,
    const float* __restrict__ Wk, const float* __restrict__ bk,
    const float* __restrict__ Wv, const float* __restrict__ bv,
    float* __restrict__ qs, float* __restrict__ ks, float* __restrict__ vs)
{
    __shared__ float xs[64][256];
    const int tid = threadIdx.x;
    const int gp  = blockIdx.x * 256 + tid;      // global pixel 0..131071
    const int b   = gp >> 16;
    const int p   = gp & 65535;
    const int base = (b << 6) * NPIX + p;        // (b*64 + c)*NPIX + p, c=0

    for (int c = 0; c < 64; ++c)
        xs[c][tid] = x[base + c * NPIX];
    __syncthreads();

    const float* Ws[3]   = {Wq, Wk, Wv};
    const float* bias[3] = {bq, bk, bv};
    float* outs[3]       = {qs, ks, vs};

    #pragma unroll
    for (int m = 0; m < 3; ++m) {
        const float* W  = Ws[m];
        const float* bb = bias[m];
        float* o        = outs[m];
        for (int og = 0; og < 4; ++og) {
            float acc[16];
            #pragma unroll
            for (int j = 0; j < 16; ++j) acc[j] = 0.f;
            #pragma unroll 4
            for (int c = 0; c < 64; ++c) {
                const float xv = xs[c][tid];
                #pragma unroll
                for (int j = 0; j < 16; ++j)
                    acc[j] += W[(og * 16 + j) * 64 + c] * xv;
            }
            #pragma unroll
            for (int j = 0; j < 16; ++j)
                o[base + (og * 16 + j) * NPIX] = acc[j] + bb[og * 16 + j];
        }
    }
}

// ---------------------------------------------------------------------------
// K2: conditioning conv (68 -> 17) + channel LayerNorm + lrelu; also emits
// xm = channel-mean of h1.
// ---------------------------------------------------------------------------
__global__ __launch_bounds__(256) void k_cond(
    const float* __restrict__ vs, const float* __restrict__ cg,
    const float* __restrict__ pinW, const float* __restrict__ pinb,
    const float* __restrict__ lnw, const float* __restrict__ lnb,
    float* __restrict__ h1, float* __restrict__ xm)
{
    const int gp = blockIdx.x * 256 + threadIdx.x;
    const int b  = gp >> 16;
    const int p  = gp & 65535;
    const int h  = p >> 8;
    const int w  = p & 255;

    float acc[17];
    #pragma unroll
    for (int oc = 0; oc < 17; ++oc) acc[oc] = pinb[oc];

    const int vbase = (b << 6) * NPIX + p;
    for (int c = 0; c < 64; ++c) {
        const float v = vs[vbase + c * NPIX];
        #pragma unroll
        for (int oc = 0; oc < 17; ++oc)
            acc[oc] += pinW[oc * 68 + c] * v;
    }
    const float c64 = cg[(b * 2 + 0) * NPIX + p];
    const float c65 = cg[(b * 2 + 1) * NPIX + p];
    const float c66 = -1.f + 2.f * (float)(h & 7) / 7.f;   // gy = lin[h%8]
    const float c67 = -1.f + 2.f * (float)(w & 7) / 7.f;   // gx = lin[w%8]
    #pragma unroll
    for (int oc = 0; oc < 17; ++oc)
        acc[oc] += pinW[oc * 68 + 64] * c64 + pinW[oc * 68 + 65] * c65 +
                   pinW[oc * 68 + 66] * c66 + pinW[oc * 68 + 67] * c67;

    float u = 0.f;
    #pragma unroll
    for (int oc = 0; oc < 17; ++oc) u += acc[oc];
    u *= (1.f / 17.f);
    float s = 0.f;
    #pragma unroll
    for (int oc = 0; oc < 17; ++oc) { const float d = acc[oc] - u; s += d * d; }
    s *= (1.f / 17.f);
    const float rstd = rsqrtf(s + 1e-6f);

    float xsum = 0.f;
    #pragma unroll
    for (int oc = 0; oc < 17; ++oc) {
        float hv = lnw[oc] * (acc[oc] - u) * rstd + lnb[oc];
        hv = (hv >= 0.f) ? hv : 0.1f * hv;   // lrelu
        h1[(b * 17 + oc) * NPIX + p] = hv;
        xsum += hv;
    }
    xm[gp] = xsum * (1.f / 17.f);
}

// ---------------------------------------------------------------------------
// K3: 3x3 conv (17 -> 1), pad 1, + sigmoid  -> sa
// ---------------------------------------------------------------------------
__global__ __launch_bounds__(256) void k_sa(
    const float* __restrict__ h1, const float* __restrict__ saW,
    const float* __restrict__ sab, float* __restrict__ sa)
{
    const int gp = blockIdx.x * 256 + threadIdx.x;
    const int b  = gp >> 16;
    const int p  = gp & 65535;
    const int h  = p >> 8;
    const int w  = p & 255;

    float acc = sab[0];
    for (int oc = 0; oc < 17; ++oc) {
        const float* base = h1 + (b * 17 + oc) * NPIX;
        #pragma unroll
        for (int ky = 0; ky < 3; ++ky) {
            const int r = h + ky - 1;
            if ((unsigned)r >= 256u) continue;
            #pragma unroll
            for (int kx = 0; kx < 3; ++kx) {
                const int c = w + kx - 1;
                if ((unsigned)c >= 256u) continue;
                acc += saW[(oc * 3 + ky) * 3 + kx] * base[r * 256 + c];
            }
        }
    }
    sa[gp] = 1.f / (1.f + __expf(-acc));
}

// ---------------------------------------------------------------------------
// K4+K5 fused: window scoring MLP + per-batch partition matching stable
// argsort(-score).  rank_i = #{score_j > score_i} + #{j<i : score_j ==
// score_i}; kept iff rank < 512.  One 1024-thread block per batch.
// ---------------------------------------------------------------------------
__global__ __launch_bounds__(1024) void k_score_select(
    const float* __restrict__ xm,
    const float* __restrict__ m1W, const float* __restrict__ m1b,
    const float* __restrict__ m2W, const float* __restrict__ m2b,
    int* __restrict__ flag, int* __restrict__ kept)
{
    __shared__ float sc[NW];
    const int b = blockIdx.x;
    const int t = threadIdx.x;          // window id 0..1023
    const int i = t >> 5;               // window row
    const int j = t & 31;               // window col

    float z[8];
    #pragma unroll
    for (int jj = 0; jj < 8; ++jj) z[jj] = m1b[jj];

    for (int a = 0; a < 8; ++a) {
        #pragma unroll
        for (int cc = 0; cc < 8; ++cc) {
            const float xv = xm[b * NPIX + (i * 8 + a) * 256 + (j * 8 + cc)];
            const int tt = a * 8 + cc;
            #pragma unroll
            for (int jj = 0; jj < 8; ++jj)
                z[jj] += m1W[jj * 64 + tt] * xv;
        }
    }
    #pragma unroll
    for (int jj = 0; jj < 8; ++jj) z[jj] = (z[jj] >= 0.f) ? z[jj] : 0.1f * z[jj];

    float l0 = m2b[0], l1 = m2b[1];
    #pragma unroll
    for (int jj = 0; jj < 8; ++jj) { l0 += m2W[jj] * z[jj]; l1 += m2W[8 + jj] * z[jj]; }
    const float mx = fmaxf(l0, l1);
    const float e0 = expf(l0 - mx), e1 = expf(l1 - mx);
    sc[t] = e0 / (e0 + e1);
    __syncthreads();

    const float s = sc[t];
    int cnt = 0;
    for (int jq = 0; jq < NW; ++jq) {
        const float sj = sc[jq];
        cnt += (sj > s) || (sj == s && jq < t);
    }
    flag[b * NW + t] = (cnt < KEEP) ? 1 : 0;
    if (cnt < KEEP) kept[b * KEEP + cnt] = t;
}

// ---------------------------------------------------------------------------
// K6: windowed attention.  1 wave per (b, kept window, head).  K/V staged in
// LDS as [d][kp] (coalesced writes; float4 broadcast reads).  SINGLE-PASS
// softmax without max-subtraction (scores are O(+-2): mathematically
// identical, exp cannot overflow).  Writes attention output in
// [token][channel] layout directly into amix (aliases qs: each thread reads
// its own q before writing the same addresses).
// ---------------------------------------------------------------------------
__global__ __launch_bounds__(64) void k_attn(
    const float* __restrict__ qs, const float* __restrict__ ks,
    const float* __restrict__ vs, const int* __restrict__ kept,
    const float* __restrict__ relh, const float* __restrict__ relw,
    float* __restrict__ amix)
{
    __shared__ float khT[16][144];
    __shared__ float vhT[16][144];

    const int b    = blockIdx.y;
    const int head = blockIdx.x & 3;
    const int win  = kept[b * KEEP + (blockIdx.x >> 2)];
    const int wy = win >> 5, wx = win & 31;
    const int t = threadIdx.x;
    const int qrow = t >> 3, qcol = t & 7;
    const int cb = ((b << 6) + head * 16) * NPIX;   // channel base (d=0)

    // stage K/V (12x12 patch, zero-padded at image border)
    for (int d = 0; d < 16; ++d) {
        for (int kp = t; kp < 144; kp += 64) {
            const int kr = kp / 12, kc = kp - kr * 12;
            const int r = wy * 8 - 2 + kr;
            const int c = wx * 8 - 2 + kc;
            float kv = 0.f, vv = 0.f;
            if ((unsigned)r < 256u && (unsigned)c < 256u) {
                const int g = cb + d * NPIX + r * 256 + c;
                kv = ks[g]; vv = vs[g];
            }
            khT[d][kp] = kv;
            vhT[d][kp] = vv;
        }
    }

    // load q (scaled)
    const int p = (wy * 8 + qrow) * 256 + (wx * 8 + qcol);
    float q[16];
    #pragma unroll
    for (int d = 0; d < 16; ++d) q[d] = qs[cb + d * NPIX + p] * 0.25f;

    // decomposed rel-pos coefficients: cw[kc] = q.rel_w[kc-qcol+11],
    // chh[kr] = q.rel_h[kr-qrow+11]
    float cw[12], chh[12];
    #pragma unroll
    for (int k = 0; k < 12; ++k) {
        const float* rw = relw + (k - qcol + 11) * 16;
        const float* rh = relh + (k - qrow + 11) * 16;
        float sw = 0.f, sh = 0.f;
        #pragma unroll
        for (int d = 0; d < 16; ++d) { sw += q[d] * rw[d]; sh += q[d] * rh[d]; }
        cw[k] = sw; chh[k] = sh;
    }
    __syncthreads();

    // single pass: exp (no max shift) + sum + PV
    float sum = 0.f;
    float vo[16];
    #pragma unroll
    for (int d = 0; d < 16; ++d) vo[d] = 0.f;
    for (int kr = 0; kr < 12; ++kr) {
        const float chr = chh[kr];
        #pragma unroll
        for (int kcq = 0; kcq < 3; ++kcq) {
            const int kp0 = kr * 12 + kcq * 4;
            float s0 = chr + cw[kcq * 4 + 0];
            float s1 = chr + cw[kcq * 4 + 1];
            float s2 = chr + cw[kcq * 4 + 2];
            float s3 = chr + cw[kcq * 4 + 3];
            #pragma unroll
            for (int d = 0; d < 16; ++d) {
                const float4 k4 = *(const float4*)&khT[d][kp0];
                s0 += q[d] * k4.x; s1 += q[d] * k4.y;
                s2 += q[d] * k4.z; s3 += q[d] * k4.w;
            }
            const float e0 = __expf(s0);
            const float e1 = __expf(s1);
            const float e2 = __expf(s2);
            const float e3 = __expf(s3);
            sum += (e0 + e1) + (e2 + e3);
            #pragma unroll
            for (int d = 0; d < 16; ++d) {
                const float4 v4 = *(const float4*)&vhT[d][kp0];
                vo[d] += e0 * v4.x + e1 * v4.y + e2 * v4.z + e3 * v4.w;
            }
        }
    }
    const float inv = 1.f / sum;
    #pragma unroll
    for (int d = 0; d < 16; ++d)
        amix[cb + d * NPIX + p] = vo[d] * inv;
}

// ---------------------------------------------------------------------------
// K7: easy path — windows NOT kept get vs * sa
// ---------------------------------------------------------------------------
__global__ __launch_bounds__(256) void k_easy(
    const float* __restrict__ vs, const float* __restrict__ sa,
    const int* __restrict__ flag, float* __restrict__ amix)
{
    const int gp = blockIdx.x * 256 + threadIdx.x;
    const int b  = gp >> 16;
    const int p  = gp & 65535;
    const int h  = p >> 8;
    const int w  = p & 255;
    const int win = (h >> 3) * 32 + (w >> 3);
    if (flag[b * NW + win]) return;   // attention path wrote these
    const float s = sa[gp];
    const int base = (b << 6) * NPIX + p;
    for (int c = 0; c < 64; ++c)
        amix[base + c * NPIX] = vs[base + c * NPIX] * s;
}

// ---------------------------------------------------------------------------
// K8: final 1x1 conv (64 -> 64)
// ---------------------------------------------------------------------------
__global__ __launch_bounds__(256) void k_out(
    const float* __restrict__ amix, const float* __restrict__ W,
    const float* __restrict__ bias, float* __restrict__ out)
{
    __shared__ float xs[64][256];
    const int tid = threadIdx.x;
    const int gp  = blockIdx.x * 256 + tid;
    const int b   = gp >> 16;
    const int p   = gp & 65535;
    const int base = (b << 6) * NPIX + p;

    for (int c = 0; c < 64; ++c)
        xs[c][tid] = amix[base + c * NPIX];
    __syncthreads();

    for (int og = 0; og < 4; ++og) {
        float acc[16];
        #pragma unroll
        for (int j = 0; j < 16; ++j) acc[j] = 0.f;
        #pragma unroll 4
        for (int c = 0; c < 64; ++c) {
            const float xv = xs[c][tid];
            #pragma unroll
            for (int j = 0; j < 16; ++j)
                acc[j] += W[(og * 16 + j) * 64 + c] * xv;
        }
        #pragma unroll
        for (int j = 0; j < 16; ++j)
            out[base + (og * 16 + j) * NPIX] = acc[j] + bias[og * 16 + j];
    }
}

// ---------------------------------------------------------------------------
extern "C" void kernel_launch(void* const* d_in, const int* in_sizes, int n_in,
                              void* d_out, int out_size, void* d_ws, size_t ws_size,
                              hipStream_t stream)
{
    const float* x    = (const float*)d_in[0];
    const float* cg   = (const float*)d_in[1];
    const float* Wq   = (const float*)d_in[2];
    const float* bq   = (const float*)d_in[3];
    const float* Wk   = (const float*)d_in[4];
    const float* bk   = (const float*)d_in[5];
    const float* Wv   = (const float*)d_in[6];
    const float* bv   = (const float*)d_in[7];
    const float* Wout = (const float*)d_in[8];
    const float* bout = (const float*)d_in[9];
    const float* relh = (const float*)d_in[10];
    const float* relw = (const float*)d_in[11];
    const float* pinW = (const float*)d_in[12];
    const float* pinb = (const float*)d_in[13];
    const float* lnw  = (const float*)d_in[14];
    const float* lnb  = (const float*)d_in[15];
    const float* saW  = (const float*)d_in[16];
    const float* sab  = (const float*)d_in[17];
    const float* m1W  = (const float*)d_in[18];
    const float* m1b  = (const float*)d_in[19];
    const float* m2W  = (const float*)d_in[20];
    const float* m2b  = (const float*)d_in[21];
    float* out = (float*)d_out;

    // workspace layout (floats); qs doubles as the assembled "amix" tensor
    float* ws    = (float*)d_ws;
    float* qs    = ws;                       // 64*NPIXT = 8388608  (aliased amix)
    float* ks    = qs + 8388608;
    float* vs    = ks + 8388608;
    float* h1    = vs + 8388608;             // 17 * NPIXT = 2228224
    float* xm    = h1 + 17 * NPIXT;          // NPIXT
    float* sa    = xm + NPIXT;               // NPIXT
    int*   flag  = (int*)(sa + NPIXT);       // 2048
    int*   kept  = flag + 2048;              // 1024

    k_qkv         <<<NPIXT / 256, 256, 0, stream>>>(x, Wq, bq, Wk, bk, Wv, bv, qs, ks, vs);
    k_cond        <<<NPIXT / 256, 256, 0, stream>>>(vs, cg, pinW, pinb, lnw, lnb, h1, xm);
    k_sa          <<<NPIXT / 256, 256, 0, stream>>>(h1, saW, sab, sa);
    k_score_select<<<2, 1024, 0, stream>>>(xm, m1W, m1b, m2W, m2b, flag, kept);
    k_attn        <<<dim3(KEEP * 4, 2), 64, 0, stream>>>(qs, ks, vs, kept, relh, relw, qs);
    k_easy        <<<NPIXT / 256, 256, 0, stream>>>(vs, sa, flag, qs);
    k_out         <<<NPIXT / 256, 256, 0, stream>>>(qs, Wout, bout, out);
}

// Round 3
// 478.298 us; speedup vs baseline: 1.1396x; 1.1396x over previous
//
#include <hip/hip_runtime.h>
#include <math.h>

// Problem constants (B=2, H=W=256, DIM=INNER=64, WS=8, OWS=12, HEADS=4, DH=16)
#define NPIX   65536      // 256*256
#define NPIXT  131072     // B * NPIX
#define NW     1024       // 32*32 windows per batch
#define KEEP   512

// ---------------------------------------------------------------------------
// K1: fused q/k/v 1x1 convs.
// ---------------------------------------------------------------------------
__global__ __launch_bounds__(256) void k_qkv(
    const float* __restrict__ x,
    const float* __restrict__ Wq, const float* __restrict__ bq,
    const float* __restrict__ Wk, const float* __restrict__ bk,
    const float* __restrict__ Wv, const float* __restrict__ bv,
    float* __restrict__ qs, float* __restrict__ ks, float* __restrict__ vs)
{
    __shared__ float xs[64][256];
    const int tid = threadIdx.x;
    const int gp  = blockIdx.x * 256 + tid;
    const int b   = gp >> 16;
    const int p   = gp & 65535;
    const int base = (b << 6) * NPIX + p;

    for (int c = 0; c < 64; ++c)
        xs[c][tid] = x[base + c * NPIX];
    __syncthreads();

    const float* Ws[3]   = {Wq, Wk, Wv};
    const float* bias[3] = {bq, bk, bv};
    float* outs[3]       = {qs, ks, vs};

    #pragma unroll
    for (int m = 0; m < 3; ++m) {
        const float* W  = Ws[m];
        const float* bb = bias[m];
        float* o        = outs[m];
        for (int og = 0; og < 4; ++og) {
            float acc[16];
            #pragma unroll
            for (int j = 0; j < 16; ++j) acc[j] = 0.f;
            #pragma unroll 4
            for (int c = 0; c < 64; ++c) {
                const float xv = xs[c][tid];
                #pragma unroll
                for (int j = 0; j < 16; ++j)
                    acc[j] += W[(og * 16 + j) * 64 + c] * xv;
            }
            #pragma unroll
            for (int j = 0; j < 16; ++j)
                o[base + (og * 16 + j) * NPIX] = acc[j] + bb[og * 16 + j];
        }
    }
}

// ---------------------------------------------------------------------------
// K2: conditioning conv (68 -> 17) + channel LayerNorm + lrelu; emits xm.
// ---------------------------------------------------------------------------
__global__ __launch_bounds__(256) void k_cond(
    const float* __restrict__ vs, const float* __restrict__ cg,
    const float* __restrict__ pinW, const float* __restrict__ pinb,
    const float* __restrict__ lnw, const float* __restrict__ lnb,
    float* __restrict__ h1, float* __restrict__ xm)
{
    const int gp = blockIdx.x * 256 + threadIdx.x;
    const int b  = gp >> 16;
    const int p  = gp & 65535;
    const int h  = p >> 8;
    const int w  = p & 255;

    float acc[17];
    #pragma unroll
    for (int oc = 0; oc < 17; ++oc) acc[oc] = pinb[oc];

    const int vbase = (b << 6) * NPIX + p;
    for (int c = 0; c < 64; ++c) {
        const float v = vs[vbase + c * NPIX];
        #pragma unroll
        for (int oc = 0; oc < 17; ++oc)
            acc[oc] += pinW[oc * 68 + c] * v;
    }
    const float c64 = cg[(b * 2 + 0) * NPIX + p];
    const float c65 = cg[(b * 2 + 1) * NPIX + p];
    const float c66 = -1.f + 2.f * (float)(h & 7) / 7.f;
    const float c67 = -1.f + 2.f * (float)(w & 7) / 7.f;
    #pragma unroll
    for (int oc = 0; oc < 17; ++oc)
        acc[oc] += pinW[oc * 68 + 64] * c64 + pinW[oc * 68 + 65] * c65 +
                   pinW[oc * 68 + 66] * c66 + pinW[oc * 68 + 67] * c67;

    float u = 0.f;
    #pragma unroll
    for (int oc = 0; oc < 17; ++oc) u += acc[oc];
    u *= (1.f / 17.f);
    float s = 0.f;
    #pragma unroll
    for (int oc = 0; oc < 17; ++oc) { const float d = acc[oc] - u; s += d * d; }
    s *= (1.f / 17.f);
    const float rstd = rsqrtf(s + 1e-6f);

    float xsum = 0.f;
    #pragma unroll
    for (int oc = 0; oc < 17; ++oc) {
        float hv = lnw[oc] * (acc[oc] - u) * rstd + lnb[oc];
        hv = (hv >= 0.f) ? hv : 0.1f * hv;
        h1[(b * 17 + oc) * NPIX + p] = hv;
        xsum += hv;
    }
    xm[gp] = xsum * (1.f / 17.f);
}

// ---------------------------------------------------------------------------
// K3: 3x3 conv (17 -> 1), pad 1, + sigmoid -> sa
// ---------------------------------------------------------------------------
__global__ __launch_bounds__(256) void k_sa(
    const float* __restrict__ h1, const float* __restrict__ saW,
    const float* __restrict__ sab, float* __restrict__ sa)
{
    const int gp = blockIdx.x * 256 + threadIdx.x;
    const int b  = gp >> 16;
    const int p  = gp & 65535;
    const int h  = p >> 8;
    const int w  = p & 255;

    float acc = sab[0];
    for (int oc = 0; oc < 17; ++oc) {
        const float* base = h1 + (b * 17 + oc) * NPIX;
        #pragma unroll
        for (int ky = 0; ky < 3; ++ky) {
            const int r = h + ky - 1;
            if ((unsigned)r >= 256u) continue;
            #pragma unroll
            for (int kx = 0; kx < 3; ++kx) {
                const int c = w + kx - 1;
                if ((unsigned)c >= 256u) continue;
                acc += saW[(oc * 3 + ky) * 3 + kx] * base[r * 256 + c];
            }
        }
    }
    sa[gp] = 1.f / (1.f + __expf(-acc));
}

// ---------------------------------------------------------------------------
// K4: window scoring MLP + stable-argsort partition (rank_i = #{s_j > s_i} +
// #{j<i : s_j == s_i}; kept iff rank < 512).  One 1024-thr block per batch.
// ---------------------------------------------------------------------------
__global__ __launch_bounds__(1024) void k_score_select(
    const float* __restrict__ xm,
    const float* __restrict__ m1W, const float* __restrict__ m1b,
    const float* __restrict__ m2W, const float* __restrict__ m2b,
    int* __restrict__ flag, int* __restrict__ kept)
{
    __shared__ float sc[NW];
    const int b = blockIdx.x;
    const int t = threadIdx.x;
    const int i = t >> 5;
    const int j = t & 31;

    float z[8];
    #pragma unroll
    for (int jj = 0; jj < 8; ++jj) z[jj] = m1b[jj];

    for (int a = 0; a < 8; ++a) {
        #pragma unroll
        for (int cc = 0; cc < 8; ++cc) {
            const float xv = xm[b * NPIX + (i * 8 + a) * 256 + (j * 8 + cc)];
            const int tt = a * 8 + cc;
            #pragma unroll
            for (int jj = 0; jj < 8; ++jj)
                z[jj] += m1W[jj * 64 + tt] * xv;
        }
    }
    #pragma unroll
    for (int jj = 0; jj < 8; ++jj) z[jj] = (z[jj] >= 0.f) ? z[jj] : 0.1f * z[jj];

    float l0 = m2b[0], l1 = m2b[1];
    #pragma unroll
    for (int jj = 0; jj < 8; ++jj) { l0 += m2W[jj] * z[jj]; l1 += m2W[8 + jj] * z[jj]; }
    const float mx = fmaxf(l0, l1);
    const float e0 = expf(l0 - mx), e1 = expf(l1 - mx);
    sc[t] = e0 / (e0 + e1);
    __syncthreads();

    const float s = sc[t];
    int cnt = 0;
    for (int jq = 0; jq < NW; ++jq) {
        const float sj = sc[jq];
        cnt += (sj > s) || (sj == s && jq < t);
    }
    flag[b * NW + t] = (cnt < KEEP) ? 1 : 0;
    if (cnt < KEEP) kept[b * KEEP + cnt] = t;
}

// ---------------------------------------------------------------------------
// K5: windowed attention — register-resident K/V + readlane broadcast.
// Block = 128 threads = 2 waves per (b, kept-window, head).  Wave w owns keys
// [72w, 72w+72): element (klocal,d) lives in kreg[klocal>>2] of lane
// 16*(klocal&3)+d.  The shared K/V operand reaches all lanes via v_readlane
// (SGPR), feeding v_fmac directly — no LDS-pipe broadcast reads in the hot
// loop.  Single-pass softmax (no max shift; scores are O(+-3)).  72*w % 12
// == 0, so kr = 6w + klocal/12: each wave needs only 6 rel_h coefficients
// (chl[6], static indices); cw[12] static too — no dynamic register indexing.
// Partial (vo,sum) combined through LDS.  Output written into amix (aliases
// qs; q read before write, disjoint across blocks).
// ---------------------------------------------------------------------------
__global__ __launch_bounds__(128, 4) void k_attn(
    const float* __restrict__ qs, const float* __restrict__ ks,
    const float* __restrict__ vs, const int* __restrict__ kept,
    const float* __restrict__ relh, const float* __restrict__ relw,
    float* __restrict__ amix)
{
    __shared__ float sK[144 * 17];   // [kp][d], pitch 17 (conflict-free)
    __shared__ float sV[144 * 17];

    const int b    = blockIdx.y;
    const int head = blockIdx.x & 3;
    const int win  = kept[b * KEEP + (blockIdx.x >> 2)];
    const int wy = win >> 5, wx = win & 31;
    const int tid  = threadIdx.x;
    const int w    = tid >> 6;       // wave id 0/1
    const int lane = tid & 63;
    const int cb = ((b << 6) + head * 16) * NPIX;

    // ---- stage 12x12 patch (zero-padded) into LDS, coalesced on pixels ----
    for (int i = tid; i < 2304; i += 128) {
        const int d  = i / 144;
        const int kp = i - d * 144;
        const int kr = kp / 12, kc = kp - kr * 12;
        const int r = wy * 8 - 2 + kr;
        const int c = wx * 8 - 2 + kc;
        float kv = 0.f, vv = 0.f;
        if ((unsigned)r < 256u && (unsigned)c < 256u) {
            const int g = cb + d * NPIX + r * 256 + c;
            kv = ks[g]; vv = vs[g];
        }
        sK[kp * 17 + d] = kv;
        sV[kp * 17 + d] = vv;
    }

    // ---- q (scaled) + rel-pos coefficients, in registers ----
    const int qrow = lane >> 3, qcol = lane & 7;
    const int p = (wy * 8 + qrow) * 256 + wx * 8 + qcol;
    float q[16];
    #pragma unroll
    for (int d = 0; d < 16; ++d) q[d] = qs[cb + d * NPIX + p] * 0.25f;

    float cw[12];
    #pragma unroll
    for (int k = 0; k < 12; ++k) {
        const float* rw = relw + (k - qcol + 11) * 16;
        float sw = 0.f;
        #pragma unroll
        for (int d = 0; d < 16; ++d) sw += q[d] * rw[d];
        cw[k] = sw;
    }
    float chl[6];   // this wave's 6 key-rows: kr = 6w + j
    #pragma unroll
    for (int j = 0; j < 6; ++j) {
        const float* rh = relh + (6 * w + j - qrow + 11) * 16;
        float sh = 0.f;
        #pragma unroll
        for (int d = 0; d < 16; ++d) sh += q[d] * rh[d];
        chl[j] = sh;
    }
    __syncthreads();

    // ---- redistribute this wave's 72 keys into registers ----
    float kreg[18], vreg[18];
    {
        const int dd = lane & 15;
        #pragma unroll
        for (int r = 0; r < 18; ++r) {
            const int kp = 72 * w + 4 * r + (lane >> 4);
            kreg[r] = sK[kp * 17 + dd];
            vreg[r] = sV[kp * 17 + dd];
        }
    }

    // ---- single-pass softmax + PV over this wave's 72 keys ----
    float sum = 0.f;
    float vo[16];
    #pragma unroll
    for (int d = 0; d < 16; ++d) vo[d] = 0.f;

    #pragma unroll
    for (int r = 0; r < 18; ++r) {
        #pragma unroll
        for (int kk = 0; kk < 4; ++kk) {
            const int kl = 4 * r + kk;          // compile-time
            float s = chl[kl / 12] + cw[kl % 12];
            #pragma unroll
            for (int d = 0; d < 16; ++d) {
                const float kv = __int_as_float(
                    __builtin_amdgcn_readlane(__float_as_int(kreg[r]), kk * 16 + d));
                s += kv * q[d];
            }
            const float e = __expf(s);
            sum += e;
            #pragma unroll
            for (int d = 0; d < 16; ++d) {
                const float vv = __int_as_float(
                    __builtin_amdgcn_readlane(__float_as_int(vreg[r]), kk * 16 + d));
                vo[d] += e * vv;
            }
        }
    }

    // ---- combine the two waves' partials via LDS (reuse sK) ----
    __syncthreads();
    float* px = sK;                 // 64 * 17 floats
    if (w == 1) {
        #pragma unroll
        for (int d = 0; d < 16; ++d) px[lane * 17 + d] = vo[d];
        px[lane * 17 + 16] = sum;
    }
    __syncthreads();
    if (w == 0) {
        sum += px[lane * 17 + 16];
        const float inv = 1.f / sum;
        #pragma unroll
        for (int d = 0; d < 16; ++d)
            amix[cb + d * NPIX + p] = (vo[d] + px[lane * 17 + d]) * inv;
    }
}

// ---------------------------------------------------------------------------
// K6: final 1x1 conv (64 -> 64), easy path fused: for non-kept windows the
// input is vs*sa (k_attn never wrote those pixels of amix).
// ---------------------------------------------------------------------------
__global__ __launch_bounds__(256) void k_out_f(
    const float* __restrict__ amix, const float* __restrict__ vs,
    const float* __restrict__ sa, const int* __restrict__ flag,
    const float* __restrict__ W, const float* __restrict__ bias,
    float* __restrict__ out)
{
    __shared__ float xs[64][256];
    const int tid = threadIdx.x;
    const int gp  = blockIdx.x * 256 + tid;
    const int b   = gp >> 16;
    const int p   = gp & 65535;
    const int h   = p >> 8;
    const int w   = p & 255;
    const int base = (b << 6) * NPIX + p;

    const int win = (h >> 3) * 32 + (w >> 3);
    const int fl  = flag[b * NW + win];
    const float mult = fl ? 1.f : sa[gp];
    const float* src = fl ? amix : vs;

    for (int c = 0; c < 64; ++c)
        xs[c][tid] = src[base + c * NPIX] * mult;
    __syncthreads();

    for (int og = 0; og < 4; ++og) {
        float acc[16];
        #pragma unroll
        for (int j = 0; j < 16; ++j) acc[j] = 0.f;
        #pragma unroll 4
        for (int c = 0; c < 64; ++c) {
            const float xv = xs[c][tid];
            #pragma unroll
            for (int j = 0; j < 16; ++j)
                acc[j] += W[(og * 16 + j) * 64 + c] * xv;
        }
        #pragma unroll
        for (int j = 0; j < 16; ++j)
            out[base + (og * 16 + j) * NPIX] = acc[j] + bias[og * 16 + j];
    }
}

// ---------------------------------------------------------------------------
extern "C" void kernel_launch(void* const* d_in, const int* in_sizes, int n_in,
                              void* d_out, int out_size, void* d_ws, size_t ws_size,
                              hipStream_t stream)
{
    const float* x    = (const float*)d_in[0];
    const float* cg   = (const float*)d_in[1];
    const float* Wq   = (const float*)d_in[2];
    const float* bq   = (const float*)d_in[3];
    const float* Wk   = (const float*)d_in[4];
    const float* bk   = (const float*)d_in[5];
    const float* Wv   = (const float*)d_in[6];
    const float* bv   = (const float*)d_in[7];
    const float* Wout = (const float*)d_in[8];
    const float* bout = (const float*)d_in[9];
    const float* relh = (const float*)d_in[10];
    const float* relw = (const float*)d_in[11];
    const float* pinW = (const float*)d_in[12];
    const float* pinb = (const float*)d_in[13];
    const float* lnw  = (const float*)d_in[14];
    const float* lnb  = (const float*)d_in[15];
    const float* saW  = (const float*)d_in[16];
    const float* sab  = (const float*)d_in[17];
    const float* m1W  = (const float*)d_in[18];
    const float* m1b  = (const float*)d_in[19];
    const float* m2W  = (const float*)d_in[20];
    const float* m2b  = (const float*)d_in[21];
    float* out = (float*)d_out;

    // workspace layout (floats); qs doubles as the assembled "amix" tensor
    float* ws    = (float*)d_ws;
    float* qs    = ws;                       // 64*NPIXT (aliased amix)
    float* ks    = qs + 8388608;
    float* vs    = ks + 8388608;
    float* h1    = vs + 8388608;             // 17 * NPIXT
    float* xm    = h1 + 17 * NPIXT;          // NPIXT
    float* sa    = xm + NPIXT;               // NPIXT
    int*   flag  = (int*)(sa + NPIXT);       // 2048
    int*   kept  = flag + 2048;              // 1024

    k_qkv         <<<NPIXT / 256, 256, 0, stream>>>(x, Wq, bq, Wk, bk, Wv, bv, qs, ks, vs);
    k_cond        <<<NPIXT / 256, 256, 0, stream>>>(vs, cg, pinW, pinb, lnw, lnb, h1, xm);
    k_sa          <<<NPIXT / 256, 256, 0, stream>>>(h1, saW, sab, sa);
    k_score_select<<<2, 1024, 0, stream>>>(xm, m1W, m1b, m2W, m2b, flag, kept);
    k_attn        <<<dim3(KEEP * 4, 2), 128, 0, stream>>>(qs, ks, vs, kept, relh, relw, qs);
    k_out_f       <<<NPIXT / 256, 256, 0, stream>>>(qs, vs, sa, flag, Wout, bout, out);
}